// Round 1
// baseline (1765.194 us; speedup 1.0000x reference)
//
#include <hip/hip_runtime.h>
#include <math.h>

#define T_SEQ 4096
#define HD 128
#define NH 4
#define DS 512
#define SCALE 0.08838834764831845f
#define BM 32
#define BN 32
#define NEG9 (-1.0e9f)

__device__ __forceinline__ float sigmoidf_(float x) {
  if (x >= 0.0f) return 1.0f / (1.0f + expf(-x));
  float e = expf(x);
  return e / (1.0f + e);
}

// ---------------- Kernel A: downsampled scores (fp32 exact) ----------------
// sds[h][id][jd] = scale * dot(Q[h][8*id], K[h][8*jd])
__global__ __launch_bounds__(256) void sds_kernel(const float* __restrict__ Q,
                                                  const float* __restrict__ K,
                                                  float* __restrict__ sds) {
  __shared__ float Qs[16][132];
  __shared__ float Ks[16][132];
  const int h = blockIdx.z;
  const int by = blockIdx.y, bx = blockIdx.x;
  const int tid = threadIdx.y * 16 + threadIdx.x;
  for (int t = tid; t < 512; t += 256) {
    int r = t >> 5, f = (t & 31) * 4;
    *(float4*)&Qs[r][f] = *(const float4*)&Q[((h * T_SEQ) + (by * 16 + r) * 8) * HD + f];
    *(float4*)&Ks[r][f] = *(const float4*)&K[((h * T_SEQ) + (bx * 16 + r) * 8) * HD + f];
  }
  __syncthreads();
  const int ty = threadIdx.y, tx = threadIdx.x;
  float acc = 0.0f;
  for (int k = 0; k < 32; ++k) {
    float4 a = *(float4*)&Qs[ty][k * 4];
    float4 b = *(float4*)&Ks[tx][k * 4];
    acc += a.x * b.x + a.y * b.y + a.z * b.z + a.w * b.w;
  }
  sds[((h * DS) + by * 16 + ty) * DS + bx * 16 + tx] = acc * SCALE;
}

// ---------------- Kernel B: exact 128th-largest per ds-row ----------------
// radix-select on sign-flipped float bits; one wave (64 lanes) per row.
__global__ __launch_bounds__(64) void thr_kernel(const float* __restrict__ sds,
                                                 float* __restrict__ thr) {
  const int row = blockIdx.x;   // h*512 + id, 2048 rows
  const int lane = threadIdx.x; // 0..63
  unsigned v[8];
  for (int t = 0; t < 8; ++t) {
    float f = sds[row * DS + t * 64 + lane];
    unsigned b = __float_as_uint(f);
    v[t] = (b & 0x80000000u) ? ~b : (b | 0x80000000u);
  }
  unsigned prefix = 0u;
  for (int bit = 31; bit >= 0; --bit) {
    unsigned cand = prefix | (1u << bit);
    int c = 0;
    for (int t = 0; t < 8; ++t) c += (v[t] >= cand) ? 1 : 0;
    for (int off = 32; off > 0; off >>= 1) c += __shfl_down(c, off, 64);
    c = __shfl(c, 0, 64);
    if (c >= 128) prefix = cand;
  }
  if (lane == 0) {
    unsigned b = (prefix & 0x80000000u) ? (prefix ^ 0x80000000u) : ~prefix;
    thr[row] = __uint_as_float(b);
  }
}

// ---------------- Kernel C: flash attention w/ block bias ----------------
__global__ __launch_bounds__(256) void attn_kernel(const float* __restrict__ Q,
                                                   const float* __restrict__ K,
                                                   const float* __restrict__ V,
                                                   const float* __restrict__ U,
                                                   const float* __restrict__ sds,
                                                   const float* __restrict__ thr,
                                                   float* __restrict__ out) {
  const int h = blockIdx.y;
  const int ib = (int)gridDim.x - 1 - (int)blockIdx.x;  // big blocks first
  const int i0 = ib * BM;
  const int tid = threadIdx.x;

  __shared__ float Qs[BM][132];
  __shared__ float Ks[BN][132];
  __shared__ float Vs[BN][132];
  __shared__ float Ps[BM][BN + 1];
  __shared__ float rowm[BM], rowl[BM], rowa[BM], roww[BM];
  __shared__ float rowu[BM], rowb[BM];
  __shared__ float biasT[BM][4];
  __shared__ int anyDead;

  // load Q tile
  for (int t = tid; t < BM * 32; t += 256) {
    int r = t >> 5, f = (t & 31) * 4;
    *(float4*)&Qs[r][f] = *(const float4*)&Q[((h * T_SEQ) + i0 + r) * HD + f];
  }
  if (tid < BM) {
    int i = i0 + tid;
    float u = U[i];
    u = fminf(fmaxf(u, 0.0f), 1.0f);
    float us = 1.0f + u;
    rowu[tid] = us;
    rowb[tid] = us * thr[h * DS + (i >> 3)];  // = u (x) thr : exact threshold element
    rowm[tid] = -INFINITY;
    rowl[tid] = 0.0f;
  }
  if (tid == 0) anyDead = 0;

  // O accumulator: thread (orow = tid>>3, ocol = (tid&7)*16) owns 16 cols of one row
  float4 o0 = {0.f, 0.f, 0.f, 0.f}, o1 = o0, o2 = o0, o3 = o0;
  const int orow = tid >> 3;
  const int ocol = (tid & 7) * 16;

  const int nc = i0 / BN + 1;
  for (int jc = 0; jc < nc; ++jc) {
    const int j0 = jc * BN;
    __syncthreads();
    // stage K,V chunk
    for (int t = tid; t < BN * 32; t += 256) {
      int r = t >> 5, f = (t & 31) * 4;
      *(float4*)&Ks[r][f] = *(const float4*)&K[((h * T_SEQ) + j0 + r) * HD + f];
      *(float4*)&Vs[r][f] = *(const float4*)&V[((h * T_SEQ) + j0 + r) * HD + f];
    }
    // per (row, jd) bias table — mirrors ref f32 ops exactly
    if (tid < BM * 4) {
      int r = tid >> 2, q = tid & 3;
      int jd = jc * 4 + q;
      int id = (i0 + r) >> 3;
      float sval = sds[((h * DS) + id) * DS + jd];
      float a = rowu[r] * sval;
      float x = (a - rowb[r]) * 10.0f;
      float m = sigmoidf_(x);
      biasT[r][q] = (1.0f - m) * NEG9;
    }
    __syncthreads();

    // S = Q K^T tile, 2x2 micro-tile per thread
    {
      const int r0 = (tid >> 4) << 1;
      const int c0 = (tid & 15) << 1;
      float d00 = 0.f, d01 = 0.f, d10 = 0.f, d11 = 0.f;
      for (int k = 0; k < 32; ++k) {
        float4 qa = *(float4*)&Qs[r0][k * 4];
        float4 qb = *(float4*)&Qs[r0 + 1][k * 4];
        float4 ka = *(float4*)&Ks[c0][k * 4];
        float4 kb = *(float4*)&Ks[c0 + 1][k * 4];
        d00 += qa.x * ka.x + qa.y * ka.y + qa.z * ka.z + qa.w * ka.w;
        d01 += qa.x * kb.x + qa.y * kb.y + qa.z * kb.z + qa.w * kb.w;
        d10 += qb.x * ka.x + qb.y * ka.y + qb.z * ka.z + qb.w * ka.w;
        d11 += qb.x * kb.x + qb.y * kb.y + qb.z * kb.z + qb.w * kb.w;
      }
      const int qi = c0 >> 3;
      int iA = i0 + r0, iB = iA + 1;
      int jA = j0 + c0, jB = jA + 1;
      Ps[r0][c0]         = (jA <= iA) ? d00 * SCALE + biasT[r0][qi]     : NEG9;
      Ps[r0][c0 + 1]     = (jB <= iA) ? d01 * SCALE + biasT[r0][qi]     : NEG9;
      Ps[r0 + 1][c0]     = (jA <= iB) ? d10 * SCALE + biasT[r0 + 1][qi] : NEG9;
      Ps[r0 + 1][c0 + 1] = (jB <= iB) ? d11 * SCALE + biasT[r0 + 1][qi] : NEG9;
    }
    __syncthreads();

    // online softmax per row
    if (tid < BM) {
      int r = tid;
      float mold = rowm[r];
      float mc = -INFINITY;
      for (int c = 0; c < BN; ++c) mc = fmaxf(mc, Ps[r][c]);
      float mnew = fmaxf(mold, mc);
      float al = expf(mold - mnew);  // -inf -> 0
      float l = rowl[r] * al;
      for (int c = 0; c < BN; ++c) {
        float p = expf(Ps[r][c] - mnew);
        Ps[r][c] = p;
        l += p;
      }
      rowm[r] = mnew; rowl[r] = l; rowa[r] = al;
    }
    __syncthreads();

    // O = O*alpha + P @ V
    {
      float al = rowa[orow];
      o0.x *= al; o0.y *= al; o0.z *= al; o0.w *= al;
      o1.x *= al; o1.y *= al; o1.z *= al; o1.w *= al;
      o2.x *= al; o2.y *= al; o2.z *= al; o2.w *= al;
      o3.x *= al; o3.y *= al; o3.z *= al; o3.w *= al;
      for (int c = 0; c < BN; ++c) {
        float p = Ps[orow][c];
        float4 v0 = *(float4*)&Vs[c][ocol];
        float4 v1 = *(float4*)&Vs[c][ocol + 4];
        float4 v2 = *(float4*)&Vs[c][ocol + 8];
        float4 v3 = *(float4*)&Vs[c][ocol + 12];
        o0.x += p * v0.x; o0.y += p * v0.y; o0.z += p * v0.z; o0.w += p * v0.w;
        o1.x += p * v1.x; o1.y += p * v1.y; o1.z += p * v1.z; o1.w += p * v1.w;
        o2.x += p * v2.x; o2.y += p * v2.y; o2.z += p * v2.z; o2.w += p * v2.w;
        o3.x += p * v3.x; o3.y += p * v3.y; o3.z += p * v3.z; o3.w += p * v3.w;
      }
    }
  }

  // non-causal tail: n_nc entries at exactly -1e9f each
  __syncthreads();
  const int endj = i0 + BN;           // == nc*BN
  const int n_nc = T_SEQ - endj;
  if (tid < BM) {
    float w = expf(NEG9 - rowm[tid]); // ==1 iff row is fully dead (m == -1e9 exactly)
    roww[tid] = w;
    rowl[tid] += (float)n_nc * w;
    if (w > 1e-6f && n_nc > 0) anyDead = 1;
  }
  __syncthreads();

  if (anyDead) {
    // rare path: dead rows need sum of V over non-causal tail
    for (int j0s = endj; j0s < T_SEQ; j0s += BN) {
      __syncthreads();
      for (int t = tid; t < BN * 32; t += 256) {
        int r = t >> 5, f = (t & 31) * 4;
        *(float4*)&Vs[r][f] = *(const float4*)&V[((h * T_SEQ) + j0s + r) * HD + f];
      }
      __syncthreads();
      float w = roww[orow];
      float4 s0 = {0.f,0.f,0.f,0.f}, s1 = s0, s2 = s0, s3 = s0;
      for (int c = 0; c < BN; ++c) {
        float4 v0 = *(float4*)&Vs[c][ocol];
        float4 v1 = *(float4*)&Vs[c][ocol + 4];
        float4 v2 = *(float4*)&Vs[c][ocol + 8];
        float4 v3 = *(float4*)&Vs[c][ocol + 12];
        s0.x += v0.x; s0.y += v0.y; s0.z += v0.z; s0.w += v0.w;
        s1.x += v1.x; s1.y += v1.y; s1.z += v1.z; s1.w += v1.w;
        s2.x += v2.x; s2.y += v2.y; s2.z += v2.z; s2.w += v2.w;
        s3.x += v3.x; s3.y += v3.y; s3.z += v3.z; s3.w += v3.w;
      }
      o0.x += w * s0.x; o0.y += w * s0.y; o0.z += w * s0.z; o0.w += w * s0.w;
      o1.x += w * s1.x; o1.y += w * s1.y; o1.z += w * s1.z; o1.w += w * s1.w;
      o2.x += w * s2.x; o2.y += w * s2.y; o2.z += w * s2.z; o2.w += w * s2.w;
      o3.x += w * s3.x; o3.y += w * s3.y; o3.z += w * s3.z; o3.w += w * s3.w;
    }
  }

  // write out
  {
    float linv = 1.0f / rowl[orow];
    float* dst = &out[((h * T_SEQ) + i0 + orow) * HD + ocol];
    float4 w0, w1, w2, w3;
    w0.x = o0.x * linv; w0.y = o0.y * linv; w0.z = o0.z * linv; w0.w = o0.w * linv;
    w1.x = o1.x * linv; w1.y = o1.y * linv; w1.z = o1.z * linv; w1.w = o1.w * linv;
    w2.x = o2.x * linv; w2.y = o2.y * linv; w2.z = o2.z * linv; w2.w = o2.w * linv;
    w3.x = o3.x * linv; w3.y = o3.y * linv; w3.z = o3.z * linv; w3.w = o3.w * linv;
    *(float4*)&dst[0]  = w0;
    *(float4*)&dst[4]  = w1;
    *(float4*)&dst[8]  = w2;
    *(float4*)&dst[12] = w3;
  }
}

extern "C" void kernel_launch(void* const* d_in, const int* in_sizes, int n_in,
                              void* d_out, int out_size, void* d_ws, size_t ws_size,
                              hipStream_t stream) {
  const float* Q = (const float*)d_in[0];
  const float* K = (const float*)d_in[1];
  const float* V = (const float*)d_in[2];
  const float* U = (const float*)d_in[3];
  float* out = (float*)d_out;

  float* sds = (float*)d_ws;                       // 4*512*512 floats = 4 MB
  float* thr = sds + (size_t)NH * DS * DS;         // 2048 floats

  dim3 gA(DS / 16, DS / 16, NH);
  dim3 bA(16, 16);
  sds_kernel<<<gA, bA, 0, stream>>>(Q, K, sds);

  thr_kernel<<<NH * DS, 64, 0, stream>>>(sds, thr);

  dim3 gC(T_SEQ / BM, NH);
  attn_kernel<<<gC, 256, 0, stream>>>(Q, K, V, U, sds, thr, out);
}

// Round 3
// 1247.379 us; speedup vs baseline: 1.4151x; 1.4151x over previous
//
#include <hip/hip_runtime.h>
#include <math.h>

#define T_SEQ 4096
#define HD 128
#define NH 4
#define DS 512
#define SCALE 0.08838834764831845f
#define NEG9 (-1.0e9f)
#define VT_STRIDE 4128   // 4096 + 32 pad so k-overrun reads stay in-row (finite poison)

typedef __attribute__((ext_vector_type(8))) _Float16 half8;
typedef __attribute__((ext_vector_type(4))) float floatx4;

__device__ __forceinline__ float sigmoidf_(float x) {
  if (x >= 0.0f) return 1.0f / (1.0f + expf(-x));
  float e = expf(x);
  return e / (1.0f + e);
}

// ---------------- fp32 -> fp16 bulk convert (Q, K) ----------------
__global__ __launch_bounds__(256) void cvt_kernel(const float* __restrict__ src,
                                                  _Float16* __restrict__ dst, int n) {
  int idx = (blockIdx.x * 256 + threadIdx.x) * 8;
  if (idx >= n) return;
  float4 a = *(const float4*)&src[idx];
  float4 b = *(const float4*)&src[idx + 4];
  half8 o;
  o[0] = (_Float16)a.x; o[1] = (_Float16)a.y; o[2] = (_Float16)a.z; o[3] = (_Float16)a.w;
  o[4] = (_Float16)b.x; o[5] = (_Float16)b.y; o[6] = (_Float16)b.z; o[7] = (_Float16)b.w;
  *(half8*)&dst[idx] = o;
}

// ---------------- V -> Vt (transposed, fp16) ----------------
__global__ __launch_bounds__(256) void vt_kernel(const float* __restrict__ V,
                                                 _Float16* __restrict__ Vt) {
  __shared__ float tile[32][33];
  int h = blockIdx.z, dt = blockIdx.y, jt = blockIdx.x;
  int tx = threadIdx.x, ty = threadIdx.y;
  for (int k = 0; k < 4; ++k) {
    int row = jt * 32 + ty + k * 8;
    tile[ty + k * 8][tx] = V[((h * T_SEQ) + row) * HD + dt * 32 + tx];
  }
  __syncthreads();
  for (int k = 0; k < 4; ++k) {
    int d = dt * 32 + ty + k * 8;
    int j = jt * 32 + tx;
    Vt[((h * HD) + d) * VT_STRIDE + j] = (_Float16)tile[tx][ty + k * 8];
  }
}

// ---------------- Kernel A: downsampled scores (fp32 exact) ----------------
__global__ __launch_bounds__(256) void sds_kernel(const float* __restrict__ Q,
                                                  const float* __restrict__ K,
                                                  float* __restrict__ sds) {
  __shared__ float Qs[16][132];
  __shared__ float Ks[16][132];
  const int h = blockIdx.z;
  const int by = blockIdx.y, bx = blockIdx.x;
  const int tid = threadIdx.y * 16 + threadIdx.x;
  for (int t = tid; t < 512; t += 256) {
    int r = t >> 5, f = (t & 31) * 4;
    *(float4*)&Qs[r][f] = *(const float4*)&Q[((h * T_SEQ) + (by * 16 + r) * 8) * HD + f];
    *(float4*)&Ks[r][f] = *(const float4*)&K[((h * T_SEQ) + (bx * 16 + r) * 8) * HD + f];
  }
  __syncthreads();
  const int ty = threadIdx.y, tx = threadIdx.x;
  float acc = 0.0f;
  for (int k = 0; k < 32; ++k) {
    float4 a = *(float4*)&Qs[ty][k * 4];
    float4 b = *(float4*)&Ks[tx][k * 4];
    acc += a.x * b.x + a.y * b.y + a.z * b.z + a.w * b.w;
  }
  sds[((h * DS) + by * 16 + ty) * DS + bx * 16 + tx] = acc * SCALE;
}

// ---------------- Kernel B: exact 128th-largest per ds-row ----------------
__global__ __launch_bounds__(64) void thr_kernel(const float* __restrict__ sds,
                                                 float* __restrict__ thr) {
  const int row = blockIdx.x;
  const int lane = threadIdx.x;
  unsigned v[8];
  for (int t = 0; t < 8; ++t) {
    float f = sds[row * DS + t * 64 + lane];
    unsigned b = __float_as_uint(f);
    v[t] = (b & 0x80000000u) ? ~b : (b | 0x80000000u);
  }
  unsigned prefix = 0u;
  for (int bit = 31; bit >= 0; --bit) {
    unsigned cand = prefix | (1u << bit);
    int c = 0;
    for (int t = 0; t < 8; ++t) c += (v[t] >= cand) ? 1 : 0;
    for (int off = 32; off > 0; off >>= 1) c += __shfl_down(c, off, 64);
    c = __shfl(c, 0, 64);
    if (c >= 128) prefix = cand;
  }
  if (lane == 0) {
    unsigned b = (prefix & 0x80000000u) ? (prefix ^ 0x80000000u) : ~prefix;
    thr[row] = __uint_as_float(b);
  }
}

// ---------------- Kernel C: MFMA flash attention w/ chunk skipping ----------------
// Block: 256 thr = 4 waves. BM=16 rows per block. Each wave owns chunks c = w mod 4
// (16 cols each) with private online-softmax state; merged at the end.
__global__ __launch_bounds__(256) void attn2_kernel(
    const _Float16* __restrict__ Qh, const _Float16* __restrict__ Kh,
    const _Float16* __restrict__ Vt, const float* __restrict__ Vf,
    const float* __restrict__ U, const float* __restrict__ sds,
    const float* __restrict__ thr, float* __restrict__ out) {
  const int h = blockIdx.y;
  const int ib = (int)gridDim.x - 1 - (int)blockIdx.x;  // heavy blocks first
  const int i0 = ib * 16;
  const int tid = threadIdx.x;
  const int w = tid >> 6;
  const int lane = tid & 63;
  const int quad = lane >> 4;
  const int n = lane & 15;

  __shared__ float Obuf[4][16][128];
  __shared__ _Float16 Ps[4][16][32];
  __shared__ float mW[4][16], lW[4][16];
  __shared__ float Vtail[128];
  __shared__ int deadFlag;

  // zero upper half of my wave's P buffer (K=32 mfma with k>=16 zero-padded)
  for (int t = 0; t < 4; ++t) {
    int r = (lane * 4 + t) >> 4;
    int c = ((lane * 4 + t) & 15) + 16;
    Ps[w][r][c] = (_Float16)0.0f;
  }
  if (tid == 0) deadFlag = 0;

  // per-row constants (rows quad*4+r), replicated across the 16 lanes of a quad
  float us[4], bb[4];
  int ids[4];
  for (int r = 0; r < 4; ++r) {
    int i = i0 + quad * 4 + r;
    float u = U[i];
    u = fminf(fmaxf(u, 0.0f), 1.0f);
    us[r] = 1.0f + u;
    ids[r] = i >> 3;
    bb[r] = us[r] * thr[h * DS + ids[r]];  // exact: fl(us*thr) == ref threshold element
  }

  // Q A-fragments, loaded once (row = i0 + n, k = dstep*32 + quad*8 + j)
  half8 qf[4];
  {
    const _Float16* qrow = &Qh[(size_t)((h * T_SEQ) + i0 + n) * HD + quad * 8];
    qf[0] = *(const half8*)&qrow[0];
    qf[1] = *(const half8*)&qrow[32];
    qf[2] = *(const half8*)&qrow[64];
    qf[3] = *(const half8*)&qrow[96];
  }

  floatx4 acc[8];
  for (int t = 0; t < 8; ++t) acc[t] = (floatx4){0.f, 0.f, 0.f, 0.f};
  float m_[4], l_[4];
  for (int r = 0; r < 4; ++r) { m_[r] = -INFINITY; l_[r] = 0.0f; }

  const int nchunks = i0 / 16 + 1;
  unsigned long long done[4] = {0ull, 0ull, 0ull, 0ull};

  for (int sweep = 0; sweep < 2; ++sweep) {
    for (int c = w; c < nchunks; c += 4) {
      if ((done[c >> 6] >> (c & 63)) & 1ull) continue;
      const int j0 = c * 16;
      // bias eval — bit-identical to the (passing) round-1 fp32 path
      float bias[4][2], bmax[4];
      for (int r = 0; r < 4; ++r) {
        for (int jj = 0; jj < 2; ++jj) {
          float sval = sds[((h * DS) + ids[r]) * DS + (c * 2 + jj)];
          float a = us[r] * sval;
          float x = (a - bb[r]) * 10.0f;
          float sg = sigmoidf_(x);
          bias[r][jj] = (1.0f - sg) * NEG9;
        }
        bmax[r] = fmaxf(bias[r][0], bias[r][1]);
      }
      // m-based skip: contributions bounded by e^(-40) relative — below fp32 relevance
      bool lane_skip = true;
      for (int r = 0; r < 4; ++r) lane_skip &= (bmax[r] + 12.0f < m_[r] - 40.0f);
      if (__all(lane_skip)) continue;
      if (sweep == 0) {  // hot-first ordering so m is established before cold re-check
        bool lane_hot = false;
        for (int r = 0; r < 4; ++r) lane_hot |= (bmax[r] > -124.0f);
        if (!__any(lane_hot)) continue;
      }
      done[c >> 6] |= 1ull << (c & 63);

      // ---- QK^T (4 mfma over d) ----
      floatx4 S = (floatx4){0.f, 0.f, 0.f, 0.f};
      {
        const _Float16* krow = &Kh[(size_t)((h * T_SEQ) + j0 + n) * HD + quad * 8];
        half8 k0 = *(const half8*)&krow[0];
        half8 k1 = *(const half8*)&krow[32];
        half8 k2 = *(const half8*)&krow[64];
        half8 k3 = *(const half8*)&krow[96];
        S = __builtin_amdgcn_mfma_f32_16x16x32_f16(qf[0], k0, S, 0, 0, 0);
        S = __builtin_amdgcn_mfma_f32_16x16x32_f16(qf[1], k1, S, 0, 0, 0);
        S = __builtin_amdgcn_mfma_f32_16x16x32_f16(qf[2], k2, S, 0, 0, 0);
        S = __builtin_amdgcn_mfma_f32_16x16x32_f16(qf[3], k3, S, 0, 0, 0);
      }
      // scores: C-layout row = quad*4+r, col = n
      const int j = j0 + n;
      const int jj = n >> 3;
      float sc[4];
      for (int r = 0; r < 4; ++r) {
        int i = i0 + quad * 4 + r;
        sc[r] = (j <= i) ? (S[r] * SCALE + bias[r][jj]) : NEG9;
      }
      // row max over the 16 lanes of the quad
      float mx[4];
      for (int r = 0; r < 4; ++r) mx[r] = sc[r];
      for (int d = 1; d < 16; d <<= 1)
        for (int r = 0; r < 4; ++r) mx[r] = fmaxf(mx[r], __shfl_xor(mx[r], d, 64));
      float p[4], alpha[4], lsum[4];
      _Float16 ph[4];
      for (int r = 0; r < 4; ++r) {
        float mnew = fmaxf(m_[r], mx[r]);
        alpha[r] = expf(m_[r] - mnew);   // -inf -> 0
        ph[r] = (_Float16)expf(sc[r] - mnew);
        p[r] = (float)ph[r];             // l accumulates the SAME value PV uses
        m_[r] = mnew;
      }
      for (int r = 0; r < 4; ++r) lsum[r] = p[r];
      for (int d = 1; d < 16; d <<= 1)
        for (int r = 0; r < 4; ++r) lsum[r] += __shfl_xor(lsum[r], d, 64);
      for (int r = 0; r < 4; ++r) l_[r] = l_[r] * alpha[r] + lsum[r];
      for (int t = 0; t < 8; ++t)
        for (int r = 0; r < 4; ++r) acc[t][r] *= alpha[r];

      // ---- P: C-layout -> A-layout via wave-private LDS ----
      for (int r = 0; r < 4; ++r) Ps[w][quad * 4 + r][n] = ph[r];
      __builtin_amdgcn_sched_barrier(0);
      __builtin_amdgcn_s_waitcnt(0);   // wave-local LDS write->read ordering
      __builtin_amdgcn_sched_barrier(0);
      half8 pf = *(half8*)&Ps[w][n][quad * 8];

      // ---- P @ V (8 mfma over d-tiles; Vt gives contiguous k) ----
      const _Float16* vbase =
          &Vt[(size_t)((h * HD) + n) * VT_STRIDE + j0 + quad * 8];
      for (int t = 0; t < 8; ++t) {
        half8 vf = *(const half8*)&vbase[(size_t)t * 16 * VT_STRIDE];
        acc[t] = __builtin_amdgcn_mfma_f32_16x16x32_f16(pf, vf, acc[t], 0, 0, 0);
      }
    }
  }

  // publish per-wave state
  if (n == 0) {
    for (int r = 0; r < 4; ++r) {
      mW[w][quad * 4 + r] = m_[r];
      lW[w][quad * 4 + r] = l_[r];
    }
  }
  for (int t = 0; t < 8; ++t)
    for (int r = 0; r < 4; ++r) Obuf[w][quad * 4 + r][t * 16 + n] = acc[t][r];
  __syncthreads();

  if (tid < 16) {
    float M = fmaxf(fmaxf(mW[0][tid], mW[1][tid]), fmaxf(mW[2][tid], mW[3][tid]));
    if (M < -1.0e8f) atomicOr(&deadFlag, 1);
  }
  __syncthreads();
  if (deadFlag) {  // rare: fully-dead rows need the uniform V tail (fp32 exact)
    if (tid < 128) {
      float s = 0.f;
      for (int jj2 = i0 + 16; jj2 < T_SEQ; ++jj2)
        s += Vf[(size_t)((h * T_SEQ) + jj2) * HD + tid];
      Vtail[tid] = s;
    }
  }
  __syncthreads();

  const float n_nc = (float)(T_SEQ - (i0 + 16));
  for (int idx = tid; idx < 16 * 128; idx += 256) {
    int r = idx >> 7, d = idx & 127;
    float M = fmaxf(fmaxf(mW[0][r], mW[1][r]), fmaxf(mW[2][r], mW[3][r]));
    float e0 = expf(mW[0][r] - M), e1 = expf(mW[1][r] - M);
    float e2 = expf(mW[2][r] - M), e3 = expf(mW[3][r] - M);
    float L = lW[0][r] * e0 + lW[1][r] * e1 + lW[2][r] * e2 + lW[3][r] * e3;
    float wdead = expf(NEG9 - M);  // ==1 iff row fully dead, else underflows to 0
    L += n_nc * wdead;
    float o = Obuf[0][r][d] * e0 + Obuf[1][r][d] * e1 + Obuf[2][r][d] * e2 +
              Obuf[3][r][d] * e3;
    if (deadFlag) o += wdead * Vtail[d];
    out[(size_t)((h * T_SEQ) + i0 + r) * HD + d] = o / L;
  }
}

extern "C" void kernel_launch(void* const* d_in, const int* in_sizes, int n_in,
                              void* d_out, int out_size, void* d_ws, size_t ws_size,
                              hipStream_t stream) {
  const float* Q = (const float*)d_in[0];
  const float* K = (const float*)d_in[1];
  const float* V = (const float*)d_in[2];
  const float* U = (const float*)d_in[3];
  float* out = (float*)d_out;

  char* wsb = (char*)d_ws;
  float* sds = (float*)wsb;                                   // 4 MB
  float* thr = (float*)(wsb + 4 * 1024 * 1024);               // 8 KB
  _Float16* Qh = (_Float16*)(wsb + 4 * 1024 * 1024 + 8192);
  _Float16* Kh = Qh + 2097152;                                // 4 MB each
  _Float16* Vt = Kh + 2097152;                                // 4.2 MB (padded)

  const int nQK = NH * T_SEQ * HD;  // 2,097,152
  cvt_kernel<<<nQK / 2048, 256, 0, stream>>>(Q, Qh, nQK);
  cvt_kernel<<<nQK / 2048, 256, 0, stream>>>(K, Kh, nQK);
  vt_kernel<<<dim3(T_SEQ / 32, HD / 32, NH), dim3(32, 8), 0, stream>>>(V, Vt);

  sds_kernel<<<dim3(DS / 16, DS / 16, NH), dim3(16, 16), 0, stream>>>(Q, K, sds);
  thr_kernel<<<NH * DS, 64, 0, stream>>>(sds, thr);

  attn2_kernel<<<dim3(T_SEQ / 16, NH), 256, 0, stream>>>(Qh, Kh, Vt, V, U, sds, thr, out);
}

// Round 4
// 684.392 us; speedup vs baseline: 2.5792x; 1.8226x over previous
//
#include <hip/hip_runtime.h>
#include <math.h>

#define T_SEQ 4096
#define HD 128
#define NH 4
#define DS 512
#define SCALE 0.08838834764831845f
#define NEG9 (-1.0e9f)
#define BN 32
#define VT_STRIDE 4096

typedef __attribute__((ext_vector_type(8))) _Float16 half8;
typedef __attribute__((ext_vector_type(4))) float floatx4;

__device__ __forceinline__ float sigmoidf_(float x) {
  if (x >= 0.0f) return 1.0f / (1.0f + expf(-x));
  float e = expf(x);
  return e / (1.0f + e);
}

// ---------------- fp32 -> fp16 bulk convert (Q, K) ----------------
__global__ __launch_bounds__(256) void cvt_kernel(const float* __restrict__ src,
                                                  _Float16* __restrict__ dst, int n) {
  int idx = (blockIdx.x * 256 + threadIdx.x) * 8;
  if (idx >= n) return;
  float4 a = *(const float4*)&src[idx];
  float4 b = *(const float4*)&src[idx + 4];
  half8 o;
  o[0] = (_Float16)a.x; o[1] = (_Float16)a.y; o[2] = (_Float16)a.z; o[3] = (_Float16)a.w;
  o[4] = (_Float16)b.x; o[5] = (_Float16)b.y; o[6] = (_Float16)b.z; o[7] = (_Float16)b.w;
  *(half8*)&dst[idx] = o;
}

// ---------------- V -> Vt (transposed, fp16) ----------------
__global__ __launch_bounds__(256) void vt_kernel(const float* __restrict__ V,
                                                 _Float16* __restrict__ Vt) {
  __shared__ float tile[32][33];
  int h = blockIdx.z, dt = blockIdx.y, jt = blockIdx.x;
  int tx = threadIdx.x, ty = threadIdx.y;
  for (int k = 0; k < 4; ++k) {
    int row = jt * 32 + ty + k * 8;
    tile[ty + k * 8][tx] = V[((h * T_SEQ) + row) * HD + dt * 32 + tx];
  }
  __syncthreads();
  for (int k = 0; k < 4; ++k) {
    int d = dt * 32 + ty + k * 8;
    int j = jt * 32 + tx;
    Vt[((size_t)(h * HD) + d) * VT_STRIDE + j] = (_Float16)tile[tx][ty + k * 8];
  }
}

// ---------------- Kernel A: downsampled scores (fp32 exact) ----------------
__global__ __launch_bounds__(256) void sds_kernel(const float* __restrict__ Q,
                                                  const float* __restrict__ K,
                                                  float* __restrict__ sds) {
  __shared__ float Qs[16][132];
  __shared__ float Ks[16][132];
  const int h = blockIdx.z;
  const int by = blockIdx.y, bx = blockIdx.x;
  const int tid = threadIdx.y * 16 + threadIdx.x;
  for (int t = tid; t < 512; t += 256) {
    int r = t >> 5, f = (t & 31) * 4;
    *(float4*)&Qs[r][f] = *(const float4*)&Q[((h * T_SEQ) + (by * 16 + r) * 8) * HD + f];
    *(float4*)&Ks[r][f] = *(const float4*)&K[((h * T_SEQ) + (bx * 16 + r) * 8) * HD + f];
  }
  __syncthreads();
  const int ty = threadIdx.y, tx = threadIdx.x;
  float acc = 0.0f;
  for (int k = 0; k < 32; ++k) {
    float4 a = *(float4*)&Qs[ty][k * 4];
    float4 b = *(float4*)&Ks[tx][k * 4];
    acc += a.x * b.x + a.y * b.y + a.z * b.z + a.w * b.w;
  }
  sds[((h * DS) + by * 16 + ty) * DS + bx * 16 + tx] = acc * SCALE;
}

// ---------------- Kernel B: exact 128th-largest per ds-row ----------------
__global__ __launch_bounds__(64) void thr_kernel(const float* __restrict__ sds,
                                                 float* __restrict__ thr) {
  const int row = blockIdx.x;
  const int lane = threadIdx.x;
  unsigned v[8];
  for (int t = 0; t < 8; ++t) {
    float f = sds[row * DS + t * 64 + lane];
    unsigned b = __float_as_uint(f);
    v[t] = (b & 0x80000000u) ? ~b : (b | 0x80000000u);
  }
  unsigned prefix = 0u;
  for (int bit = 31; bit >= 0; --bit) {
    unsigned cand = prefix | (1u << bit);
    int c = 0;
    for (int t = 0; t < 8; ++t) c += (v[t] >= cand) ? 1 : 0;
    for (int off = 32; off > 0; off >>= 1) c += __shfl_down(c, off, 64);
    c = __shfl(c, 0, 64);
    if (c >= 128) prefix = cand;
  }
  if (lane == 0) {
    unsigned b = (prefix & 0x80000000u) ? (prefix ^ 0x80000000u) : ~prefix;
    thr[row] = __uint_as_float(b);
  }
}

// ---------------- Kernel C: MFMA flash attention, BN=32 chunks ----------------
// 4 waves per block, BM=16 rows. Wave w owns chunks c = w + 4*cc (32 cols each),
// private online-softmax state, merged at the end. doneMask lives in SGPRs
// (wave-uniform cc) — the round-3 done[4] array was dynamically indexed (scratch).
__global__ __launch_bounds__(256) void attn3_kernel(
    const _Float16* __restrict__ Qh, const _Float16* __restrict__ Kh,
    const _Float16* __restrict__ Vt, const float* __restrict__ Vf,
    const float* __restrict__ U, const float* __restrict__ sds,
    const float* __restrict__ thr, float* __restrict__ out) {
  const int h = blockIdx.y;
  const int ib = (int)gridDim.x - 1 - (int)blockIdx.x;  // heavy blocks first
  const int i0 = ib * 16;
  const int tid = threadIdx.x;
  const int w = tid >> 6;
  const int lane = tid & 63;
  const int quad = lane >> 4;
  const int n = lane & 15;

  __shared__ float Obuf[4][16][128];
  __shared__ _Float16 Ps[4][16][32];
  __shared__ float mW[4][16], lW[4][16];
  __shared__ float VtailS[2][128];
  __shared__ int deadFlag;

  if (tid == 0) deadFlag = 0;

  // per-row constants (rows quad*4+r). All 4 rows of a quad share one ds-row.
  const int myid = (i0 >> 3) + (quad >> 1);
  float us[4], bb[4];
  for (int r = 0; r < 4; ++r) {
    int i = i0 + quad * 4 + r;
    float u = U[i];
    u = fminf(fmaxf(u, 0.0f), 1.0f);
    us[r] = 1.0f + u;
    bb[r] = us[r] * thr[h * DS + myid];  // exact: fl(us*thr) == ref threshold element
  }

  // Q A-fragments (row = i0 + n, k = dstep*32 + quad*8 + j)
  half8 qf[4];
  {
    const _Float16* qrow = &Qh[(size_t)((h * T_SEQ) + i0 + n) * HD + quad * 8];
    qf[0] = *(const half8*)&qrow[0];
    qf[1] = *(const half8*)&qrow[32];
    qf[2] = *(const half8*)&qrow[64];
    qf[3] = *(const half8*)&qrow[96];
  }

  floatx4 acc[8];
  for (int t = 0; t < 8; ++t) acc[t] = (floatx4){0.f, 0.f, 0.f, 0.f};
  float m_[4], l_[4];
  for (int r = 0; r < 4; ++r) { m_[r] = -INFINITY; l_[r] = 0.0f; }

  const int nchunks = i0 / BN + 1;
  const int nMine = (nchunks > w) ? ((nchunks - w + 3) >> 2) : 0;
  unsigned long long doneMask = 0ull;

  for (int sweep = 0; sweep < 2; ++sweep) {
    for (int cc = 0; cc < nMine; ++cc) {
      if ((doneMask >> cc) & 1ull) continue;
      const int c = w + (cc << 2);
      const int j0 = c * BN;

      // ---- bias: 2 sds loads/lane, 8 sigmoids (bit-identical fp32 sequence) ----
      const int jdA = (c << 2) + (n >> 3);
      float svA = sds[((h * DS) + myid) * DS + jdA];
      float svB = sds[((h * DS) + myid) * DS + jdA + 2];
      float biasA[4], biasB[4], bm[4];
      for (int r = 0; r < 4; ++r) {
        float aA = us[r] * svA;
        float xA = (aA - bb[r]) * 10.0f;
        biasA[r] = (1.0f - sigmoidf_(xA)) * NEG9;
        float aB = us[r] * svB;
        float xB = (aB - bb[r]) * 10.0f;
        biasB[r] = (1.0f - sigmoidf_(xB)) * NEG9;
        bm[r] = fmaxf(biasA[r], biasB[r]);
      }
      // per-row max over all 4 ds cols of the chunk (xor 8 flips the jd pair)
      for (int r = 0; r < 4; ++r) bm[r] = fmaxf(bm[r], __shfl_xor(bm[r], 8, 64));

      bool ls = true, lh = false;
      for (int r = 0; r < 4; ++r) {
        ls &= (bm[r] + 12.0f < m_[r] - 40.0f);  // contribution < e^-40 relative
        lh |= (bm[r] > -124.0f);
      }
      if (__all(ls)) continue;                 // skip (revisit in sweep 1)
      if (sweep == 0 && !__any(lh)) continue;  // defer cold chunks to sweep 1
      doneMask |= 1ull << cc;

      // ---- QK^T: 8 mfma (4 d-steps x 2 col-tiles) ----
      floatx4 S0 = (floatx4){0.f, 0.f, 0.f, 0.f};
      floatx4 S1 = (floatx4){0.f, 0.f, 0.f, 0.f};
      {
        const _Float16* kr0 = &Kh[(size_t)((h * T_SEQ) + j0 + n) * HD + quad * 8];
        const _Float16* kr1 = kr0 + 16 * HD;
        for (int d = 0; d < 4; ++d) {
          half8 ka = *(const half8*)&kr0[d * 32];
          half8 kb = *(const half8*)&kr1[d * 32];
          S0 = __builtin_amdgcn_mfma_f32_16x16x32_f16(qf[d], ka, S0, 0, 0, 0);
          S1 = __builtin_amdgcn_mfma_f32_16x16x32_f16(qf[d], kb, S1, 0, 0, 0);
        }
      }
      // scores: C-layout row = quad*4+r, col = n (S0: j0+n, S1: j0+16+n)
      const int jA = j0 + n, jB = j0 + 16 + n;
      float sc0[4], sc1[4];
      for (int r = 0; r < 4; ++r) {
        int i = i0 + quad * 4 + r;
        sc0[r] = (jA <= i) ? (S0[r] * SCALE + biasA[r]) : NEG9;
        sc1[r] = (jB <= i) ? (S1[r] * SCALE + biasB[r]) : NEG9;
      }
      float mx[4];
      for (int r = 0; r < 4; ++r) mx[r] = fmaxf(sc0[r], sc1[r]);
      for (int d = 1; d < 16; d <<= 1)
        for (int r = 0; r < 4; ++r) mx[r] = fmaxf(mx[r], __shfl_xor(mx[r], d, 64));
      float alpha[4], lsum[4];
      _Float16 ph0[4], ph1[4];
      for (int r = 0; r < 4; ++r) {
        float mnew = fmaxf(m_[r], mx[r]);
        alpha[r] = expf(m_[r] - mnew);  // -inf -> 0
        ph0[r] = (_Float16)expf(sc0[r] - mnew);
        ph1[r] = (_Float16)expf(sc1[r] - mnew);
        lsum[r] = (float)ph0[r] + (float)ph1[r];  // l consistent with PV numerator
        m_[r] = mnew;
      }
      for (int d = 1; d < 16; d <<= 1)
        for (int r = 0; r < 4; ++r) lsum[r] += __shfl_xor(lsum[r], d, 64);
      for (int r = 0; r < 4; ++r) l_[r] = l_[r] * alpha[r] + lsum[r];
      for (int t = 0; t < 8; ++t)
        for (int r = 0; r < 4; ++r) acc[t][r] *= alpha[r];

      // ---- P: C-layout -> A-layout via wave-private LDS (full K=32, no pad) ----
      for (int r = 0; r < 4; ++r) {
        Ps[w][quad * 4 + r][n] = ph0[r];
        Ps[w][quad * 4 + r][n + 16] = ph1[r];
      }
      __builtin_amdgcn_sched_barrier(0);
      __builtin_amdgcn_s_waitcnt(0xC07F);  // lgkmcnt(0) only — don't drain vmcnt
      __builtin_amdgcn_sched_barrier(0);
      half8 pf = *(half8*)&Ps[w][n][quad * 8];

      // ---- P @ V: 8 mfma over d-tiles, full K=32 of real data ----
      const _Float16* vbase =
          &Vt[(size_t)((h * HD) + n) * VT_STRIDE + j0 + quad * 8];
      for (int t = 0; t < 8; ++t) {
        half8 vf = *(const half8*)&vbase[(size_t)t * 16 * VT_STRIDE];
        acc[t] = __builtin_amdgcn_mfma_f32_16x16x32_f16(pf, vf, acc[t], 0, 0, 0);
      }
    }
  }

  // publish per-wave state
  if (n == 0) {
    for (int r = 0; r < 4; ++r) {
      mW[w][quad * 4 + r] = m_[r];
      lW[w][quad * 4 + r] = l_[r];
    }
  }
  for (int t = 0; t < 8; ++t)
    for (int r = 0; r < 4; ++r) Obuf[w][quad * 4 + r][t * 16 + n] = acc[t][r];
  __syncthreads();

  if (tid < 16) {
    float M = fmaxf(fmaxf(mW[0][tid], mW[1][tid]), fmaxf(mW[2][tid], mW[3][tid]));
    if (M < -1.0e8f) atomicOr(&deadFlag, 1);
  }
  __syncthreads();

  const int jcov = BN * nchunks;  // columns covered by the chunk loop
  if (deadFlag) {  // rare: fully-dead rows need the uniform V tail (fp32)
    int d = tid & 127, hlf = tid >> 7;
    float s = 0.f;
    for (int j = jcov + hlf; j < T_SEQ; j += 2)
      s += Vf[(size_t)((h * T_SEQ) + j) * HD + d];
    VtailS[hlf][d] = s;
  }
  __syncthreads();

  const float n_nc = (float)(T_SEQ - jcov);
  for (int idx = tid; idx < 16 * 128; idx += 256) {
    int r = idx >> 7, d = idx & 127;
    float M = fmaxf(fmaxf(mW[0][r], mW[1][r]), fmaxf(mW[2][r], mW[3][r]));
    float e0 = expf(mW[0][r] - M), e1 = expf(mW[1][r] - M);
    float e2 = expf(mW[2][r] - M), e3 = expf(mW[3][r] - M);
    float L = lW[0][r] * e0 + lW[1][r] * e1 + lW[2][r] * e2 + lW[3][r] * e3;
    float wdead = expf(NEG9 - M);  // ==1 iff row fully dead, else 0
    L += n_nc * wdead;
    float o = Obuf[0][r][d] * e0 + Obuf[1][r][d] * e1 + Obuf[2][r][d] * e2 +
              Obuf[3][r][d] * e3;
    if (deadFlag) o += wdead * (VtailS[0][d] + VtailS[1][d]);
    out[(size_t)((h * T_SEQ) + i0 + r) * HD + d] = o / L;
  }
}

extern "C" void kernel_launch(void* const* d_in, const int* in_sizes, int n_in,
                              void* d_out, int out_size, void* d_ws, size_t ws_size,
                              hipStream_t stream) {
  const float* Q = (const float*)d_in[0];
  const float* K = (const float*)d_in[1];
  const float* V = (const float*)d_in[2];
  const float* U = (const float*)d_in[3];
  float* out = (float*)d_out;

  char* wsb = (char*)d_ws;
  float* sds = (float*)wsb;                                   // 4 MB
  float* thr = (float*)(wsb + 4 * 1024 * 1024);               // 8 KB
  _Float16* Qh = (_Float16*)(wsb + 4 * 1024 * 1024 + 8192);
  _Float16* Kh = Qh + 2097152;                                // 4 MB each
  _Float16* Vt = Kh + 2097152;                                // 4 MB

  const int nQK = NH * T_SEQ * HD;  // 2,097,152
  cvt_kernel<<<nQK / 2048, 256, 0, stream>>>(Q, Qh, nQK);
  cvt_kernel<<<nQK / 2048, 256, 0, stream>>>(K, Kh, nQK);
  vt_kernel<<<dim3(T_SEQ / 32, HD / 32, NH), dim3(32, 8), 0, stream>>>(V, Vt);

  sds_kernel<<<dim3(DS / 16, DS / 16, NH), dim3(16, 16), 0, stream>>>(Q, K, sds);
  thr_kernel<<<NH * DS, 64, 0, stream>>>(sds, thr);

  attn3_kernel<<<dim3(T_SEQ / 16, NH), 256, 0, stream>>>(Qh, Kh, Vt, V, U, sds, thr, out);
}